// Round 1
// baseline (2261.674 us; speedup 1.0000x reference)
//
#include <hip/hip_runtime.h>
#include <hip/hip_bf16.h>

// Problem constants
#define NN    32768
#define EE    98304
#define FN    32
#define FEDGE 16
#define DD    64
#define OUTD  16
#define GG    64
#define EPSL  1e-5f

// ---------------------------------------------------------------------------
// fc1: hx[n][d] = x[n][:32] @ fc1_w + fc1_b          (64 d-lanes x 4 nodes/blk)
// ---------------------------------------------------------------------------
__global__ __launch_bounds__(256) void k_fc1(const float* __restrict__ x,
                                             const float* __restrict__ w,
                                             const float* __restrict__ b,
                                             float* __restrict__ hx) {
    int t = threadIdx.x;
    int d = t & 63;
    int n = blockIdx.x * 4 + (t >> 6);          // n wave-uniform -> x row scalar-loads
    const float* xr = x + n * FN;
    float acc = b[d];
    #pragma unroll
    for (int i = 0; i < FN; ++i) acc += xr[i] * w[i * DD + d];
    hx[n * DD + d] = acc;
}

// ---------------------------------------------------------------------------
// edge MLP: het[k][e] = relu(ea[e][:16] @ w1 + b1),  het[64][e] = 1.0
// stored transposed (k-major) in bf16 so the conv kernel reads h for a fixed k
// across 64 consecutive edges (coalesced).
// ---------------------------------------------------------------------------
__global__ __launch_bounds__(256) void k_mlp(const float* __restrict__ ea,
                                             const float* __restrict__ w1,
                                             const float* __restrict__ b1,
                                             __hip_bfloat16* __restrict__ het) {
    __shared__ float eas[256][17];              // +1 pad: conflict-free row reads
    int t = threadIdx.x;
    int e0 = blockIdx.x * 256;
    const float4* src = (const float4*)(ea + e0 * FEDGE);
    #pragma unroll
    for (int j = 0; j < 4; ++j) {
        float4 v = src[t + 256 * j];
        int f = (t + 256 * j) * 4;
        int e = f >> 4, i = f & 15;
        eas[e][i] = v.x; eas[e][i + 1] = v.y; eas[e][i + 2] = v.z; eas[e][i + 3] = v.w;
    }
    __syncthreads();
    int e = e0 + t;
    float a[FEDGE];
    #pragma unroll
    for (int i = 0; i < FEDGE; ++i) a[i] = eas[t][i];
    for (int k = 0; k < DD; ++k) {
        float acc = b1[k];
        #pragma unroll
        for (int i = 0; i < FEDGE; ++i) acc += a[i] * w1[i * DD + k];
        acc = fmaxf(acc, 0.0f);
        het[k * EE + e] = __float2bfloat16(acc);
    }
    het[DD * EE + e] = __float2bfloat16(1.0f);  // virtual k=64 slice (b2 term)
}

// ---------------------------------------------------------------------------
// agg init: agg[n][o] = xin[n][:] @ root + bias   (root/self term, also zeroes)
// ---------------------------------------------------------------------------
__global__ __launch_bounds__(256) void k_agginit(const float* __restrict__ xin,
                                                 const float* __restrict__ root,
                                                 const float* __restrict__ bias,
                                                 float* __restrict__ agg) {
    int t = threadIdx.x;
    int o = t & 63;
    int n = blockIdx.x * 4 + (t >> 6);
    const float* xr = xin + n * DD;
    float acc = bias[o];
    #pragma unroll
    for (int i = 0; i < DD; ++i) acc += xr[i] * root[i * DD + o];
    agg[n * DD + o] = acc;
}

// ---------------------------------------------------------------------------
// conv: per block 64 edges x 64 outputs.
//   msg[e][o] = sum_{k=0..64} h[e,k] * sum_i xs[src[e]][i] * W2k[i][o]
// where k<64 -> W2k = w2[k] (16KB contiguous slice), k=64 -> b2 (h==1).
// Accumulate into agg[dst[e]][o] via atomics.
// Thread t: edge el = t>>2, output quarter q = t&3 (16 outputs in regs).
// ---------------------------------------------------------------------------
__global__ __launch_bounds__(256) void k_conv(const float* __restrict__ xs,
                                              const __hip_bfloat16* __restrict__ het,
                                              const float* __restrict__ w2,
                                              const float* __restrict__ b2,
                                              const int* __restrict__ ei,
                                              float* __restrict__ agg) {
    __shared__ float xss[64][68];               // pad 68: 16B-aligned rows, 2-way max
    __shared__ float w2s[64][68];
    int t = threadIdx.x;
    int e0 = blockIdx.x * 64;
    int el = t >> 2, q = t & 3;
    int o0 = q * 16;

    // stage xs rows (gather via src index)
    int s = ei[e0 + el];
    const float4* xr = (const float4*)(xs + s * DD + o0);
    #pragma unroll
    for (int j = 0; j < 4; ++j) {
        *(float4*)&xss[el][o0 + j * 4] = xr[j];
    }

    float acc[16];
    #pragma unroll
    for (int j = 0; j < 16; ++j) acc[j] = 0.0f;

    for (int k = 0; k <= DD; ++k) {
        const float* wsrc = (k < DD) ? (w2 + k * (DD * DD)) : b2;
        __syncthreads();                        // prior iter done reading w2s
        #pragma unroll
        for (int j = 0; j < 4; ++j) {
            int f = (t + 256 * j) * 4;          // 4096 floats of this k-slice
            float4 v = *(const float4*)(wsrc + f);
            *(float4*)&w2s[f >> 6][f & 63] = v;
        }
        __syncthreads();                        // also covers xss on k==0

        float hv = __bfloat162float(het[k * EE + e0 + el]);
        float tmp[16];
        #pragma unroll
        for (int j = 0; j < 16; ++j) tmp[j] = 0.0f;
        for (int i = 0; i < DD; ++i) {
            float xv = xss[el][i];
            const float4* wr4 = (const float4*)&w2s[i][o0];
            float4 wa = wr4[0], wb = wr4[1], wc = wr4[2], wd = wr4[3];
            tmp[0]  += xv * wa.x; tmp[1]  += xv * wa.y; tmp[2]  += xv * wa.z; tmp[3]  += xv * wa.w;
            tmp[4]  += xv * wb.x; tmp[5]  += xv * wb.y; tmp[6]  += xv * wb.z; tmp[7]  += xv * wb.w;
            tmp[8]  += xv * wc.x; tmp[9]  += xv * wc.y; tmp[10] += xv * wc.z; tmp[11] += xv * wc.w;
            tmp[12] += xv * wd.x; tmp[13] += xv * wd.y; tmp[14] += xv * wd.z; tmp[15] += xv * wd.w;
        }
        #pragma unroll
        for (int j = 0; j < 16; ++j) acc[j] += hv * tmp[j];
    }

    int dst = ei[EE + e0 + el];
    float* ar = agg + dst * DD + o0;
    #pragma unroll
    for (int j = 0; j < 16; ++j) atomicAdd(&ar[j], acc[j]);
}

// ---------------------------------------------------------------------------
// LN reduce: global sum and sum-of-squares over N*DD elems -> stats[0],[1]
// ---------------------------------------------------------------------------
__global__ __launch_bounds__(256) void k_lnred(const float* __restrict__ v,
                                               float* __restrict__ stats) {
    int t = threadIdx.x;
    int base = blockIdx.x * 4096 + t;
    float s = 0.0f, s2 = 0.0f;
    #pragma unroll
    for (int j = 0; j < 16; ++j) {
        float x = v[base + j * 256];
        s += x; s2 += x * x;
    }
    #pragma unroll
    for (int off = 32; off > 0; off >>= 1) {
        s  += __shfl_down(s, off, 64);
        s2 += __shfl_down(s2, off, 64);
    }
    __shared__ float ps[8];
    int w = t >> 6;
    if ((t & 63) == 0) { ps[w] = s; ps[4 + w] = s2; }
    __syncthreads();
    if (t == 0) {
        atomicAdd(&stats[0], ps[0] + ps[1] + ps[2] + ps[3]);
        atomicAdd(&stats[1], ps[4] + ps[5] + ps[6] + ps[7]);
    }
}

// ---------------------------------------------------------------------------
// LN apply (in place) + relu:  v = relu((v-mean)/(std+eps)*gw[d] + gb[d])
// NOTE: reference divides by (std + eps), NOT sqrt(var+eps).
// ---------------------------------------------------------------------------
__global__ __launch_bounds__(256) void k_lnapply(float* __restrict__ v,
                                                 const float* __restrict__ stats,
                                                 const float* __restrict__ gw,
                                                 const float* __restrict__ gb) {
    const float M = (float)(NN * DD);
    float mean = stats[0] / M;
    float var  = stats[1] / M - mean * mean;
    float rden = 1.0f / (sqrtf(fmaxf(var, 0.0f)) + EPSL);
    int t = threadIdx.x;
    int base = blockIdx.x * 1024 + t;
    #pragma unroll
    for (int j = 0; j < 4; ++j) {
        int idx = base + j * 256;
        int d = idx & 63;
        float x = v[idx];
        v[idx] = fmaxf((x - mean) * rden * gw[d] + gb[d], 0.0f);
    }
}

// ---------------------------------------------------------------------------
// pool: segment-sum h by (sorted) batch + counts, via run-compressed atomics
// ---------------------------------------------------------------------------
__global__ __launch_bounds__(256) void k_pool(const float* __restrict__ h,
                                              const int* __restrict__ batch,
                                              float* __restrict__ pool,
                                              float* __restrict__ cnt) {
    int t = threadIdx.x;
    int d = t & 63;
    int ln = t >> 6;                            // 0..3
    int n0 = blockIdx.x * 256;
    float s = 0.0f, sc = 0.0f;
    int cur = batch[n0 + ln];
    for (int j = 0; j < 64; ++j) {
        int n = n0 + ln + j * 4;
        int b = batch[n];
        if (b != cur) {
            atomicAdd(&pool[cur * DD + d], s);
            if (d == 0) atomicAdd(&cnt[cur], sc);
            s = 0.0f; sc = 0.0f; cur = b;
        }
        s  += h[n * DD + d];
        sc += 1.0f;
    }
    atomicAdd(&pool[cur * DD + d], s);
    if (d == 0) atomicAdd(&cnt[cur], sc);
}

// ---------------------------------------------------------------------------
// fc2: out[g][o] = (pool[g]/max(cnt,1)) @ fc2_w + fc2_b     (single block)
// ---------------------------------------------------------------------------
__global__ __launch_bounds__(256) void k_fc2(const float* __restrict__ pool,
                                             const float* __restrict__ cnt,
                                             const float* __restrict__ w,
                                             const float* __restrict__ b,
                                             float* __restrict__ out) {
    int t = threadIdx.x;
    int o = t & 15;
    int g0 = t >> 4;                            // 0..15
    #pragma unroll
    for (int gg = 0; gg < 4; ++gg) {
        int g = g0 + gg * 16;
        float inv = 1.0f / fmaxf(cnt[g], 1.0f);
        float acc = b[o];
        for (int d = 0; d < DD; ++d)
            acc += pool[g * DD + d] * inv * w[d * OUTD + o];
        out[g * OUTD + o] = acc;
    }
}

// ---------------------------------------------------------------------------
extern "C" void kernel_launch(void* const* d_in, const int* in_sizes, int n_in,
                              void* d_out, int out_size, void* d_ws, size_t ws_size,
                              hipStream_t stream) {
    const float* x       = (const float*)d_in[0];
    const float* ea      = (const float*)d_in[1];
    const int*   ei      = (const int*)d_in[2];
    const int*   batch   = (const int*)d_in[3];
    const float* fc1_w   = (const float*)d_in[4];
    const float* fc1_b   = (const float*)d_in[5];
    const float* e1w1    = (const float*)d_in[6];
    const float* e1b1    = (const float*)d_in[7];
    const float* e1w2    = (const float*)d_in[8];
    const float* e1b2    = (const float*)d_in[9];
    const float* root1   = (const float*)d_in[10];
    const float* bias1   = (const float*)d_in[11];
    const float* gn1w    = (const float*)d_in[12];
    const float* gn1b    = (const float*)d_in[13];
    const float* e2w1    = (const float*)d_in[14];
    const float* e2b1    = (const float*)d_in[15];
    const float* e2w2    = (const float*)d_in[16];
    const float* e2b2    = (const float*)d_in[17];
    const float* root2   = (const float*)d_in[18];
    const float* bias2   = (const float*)d_in[19];
    const float* gn2w    = (const float*)d_in[20];
    const float* gn2b    = (const float*)d_in[21];
    const float* fc2_w   = (const float*)d_in[22];
    const float* fc2_b   = (const float*)d_in[23];
    float* out = (float*)d_out;

    // workspace layout (bytes)
    char* ws = (char*)d_ws;
    float*          hx    = (float*)(ws);                         // N*64 f32 (8 MB) -> later agg2/h2
    float*          agg1  = (float*)(ws + 8388608);               // N*64 f32 (8 MB) -> h1
    __hip_bfloat16* het   = (__hip_bfloat16*)(ws + 16777216);     // 65*E bf16 (12.8 MB), reused per layer
    float*          pool  = (float*)(ws + 29556736);              // 64*64 f32
    float*          cnt   = (float*)(ws + 29573120);              // 64 f32
    float*          stats = (float*)(ws + 29573376);              // 4 f32
    float*          agg2  = hx;                                   // reuse: hx dead after conv1

    // zero pool/cnt/stats (re-poisoned 0xAA every call)
    hipMemsetAsync(ws + 29556736, 0, 16384 + 256 + 16, stream);

    // ---- layer 1 ----
    k_fc1<<<NN / 4, 256, 0, stream>>>(x, fc1_w, fc1_b, hx);
    k_mlp<<<EE / 256, 256, 0, stream>>>(ea, e1w1, e1b1, het);
    k_agginit<<<NN / 4, 256, 0, stream>>>(hx, root1, bias1, agg1);
    k_conv<<<EE / 64, 256, 0, stream>>>(hx, het, e1w2, e1b2, ei, agg1);
    k_lnred<<<(NN * DD) / 4096, 256, 0, stream>>>(agg1, stats);
    k_lnapply<<<(NN * DD) / 1024, 256, 0, stream>>>(agg1, stats, gn1w, gn1b);

    // ---- layer 2 ----  (h1 == agg1 in place; agg2 reuses hx buffer)
    k_mlp<<<EE / 256, 256, 0, stream>>>(ea, e2w1, e2b1, het);
    k_agginit<<<NN / 4, 256, 0, stream>>>(agg1, root2, bias2, agg2);
    k_conv<<<EE / 64, 256, 0, stream>>>(agg1, het, e2w2, e2b2, ei, agg2);
    k_lnred<<<(NN * DD) / 4096, 256, 0, stream>>>(agg2, stats + 2);
    k_lnapply<<<(NN * DD) / 1024, 256, 0, stream>>>(agg2, stats + 2, gn2w, gn2b);

    // ---- pool + fc2 ----
    k_pool<<<NN / 256, 256, 0, stream>>>(agg2, batch, pool, cnt);
    k_fc2<<<1, 256, 0, stream>>>(pool, cnt, fc2_w, fc2_b, out);
}

// Round 2
// 444.119 us; speedup vs baseline: 5.0925x; 5.0925x over previous
//
#include <hip/hip_runtime.h>
#include <hip/hip_bf16.h>

// Problem constants
#define NN    32768
#define EE    98304
#define FN    32
#define FEDGE 16
#define DD    64
#define OUTD  16
#define GG    64
#define EPSL  1e-5f

typedef __attribute__((ext_vector_type(8))) short bf16x8;
typedef __attribute__((ext_vector_type(4))) float f32x4;

__device__ __forceinline__ void gload_lds16(const void* g, void* l) {
    __builtin_amdgcn_global_load_lds(
        (const __attribute__((address_space(1))) void*)g,
        (__attribute__((address_space(3))) void*)l, 16, 0, 0);
}

__device__ __forceinline__ ushort f2bf(float f) {
    __hip_bfloat16 b = __float2bfloat16(f);
    return *(ushort*)&b;
}

// ---------------------------------------------------------------------------
// fc1: hx[n][d] = x[n][:32] @ fc1_w + fc1_b
// ---------------------------------------------------------------------------
__global__ __launch_bounds__(256) void k_fc1(const float* __restrict__ x,
                                             const float* __restrict__ w,
                                             const float* __restrict__ b,
                                             float* __restrict__ hx) {
    int t = threadIdx.x;
    int d = t & 63;
    int n = blockIdx.x * 4 + (t >> 6);
    const float* xr = x + n * FN;
    float acc = b[d];
    #pragma unroll
    for (int i = 0; i < FN; ++i) acc += xr[i] * w[i * DD + d];
    hx[n * DD + d] = acc;
}

// ---------------------------------------------------------------------------
// edge MLP: het[k][e] = relu(ea[e][:16] @ w1 + b1),  het[64][e] = 1.0
// ---------------------------------------------------------------------------
__global__ __launch_bounds__(256) void k_mlp(const float* __restrict__ ea,
                                             const float* __restrict__ w1,
                                             const float* __restrict__ b1,
                                             __hip_bfloat16* __restrict__ het) {
    __shared__ float eas[256][17];
    int t = threadIdx.x;
    int e0 = blockIdx.x * 256;
    const float4* src = (const float4*)(ea + e0 * FEDGE);
    #pragma unroll
    for (int j = 0; j < 4; ++j) {
        float4 v = src[t + 256 * j];
        int f = (t + 256 * j) * 4;
        int e = f >> 4, i = f & 15;
        eas[e][i] = v.x; eas[e][i + 1] = v.y; eas[e][i + 2] = v.z; eas[e][i + 3] = v.w;
    }
    __syncthreads();
    int e = e0 + t;
    float a[FEDGE];
    #pragma unroll
    for (int i = 0; i < FEDGE; ++i) a[i] = eas[t][i];
    for (int k = 0; k < DD; ++k) {
        float acc = b1[k];
        #pragma unroll
        for (int i = 0; i < FEDGE; ++i) acc += a[i] * w1[i * DD + k];
        acc = fmaxf(acc, 0.0f);
        het[k * EE + e] = __float2bfloat16(acc);
    }
    het[DD * EE + e] = __float2bfloat16(1.0f);
}

// ---------------------------------------------------------------------------
// prep: w2t[s][o][i^((o&7)<<3)] = bf16(slice_s[i][o]);  slice 64 = b2.
// Linear image is what conv's global_load_lds copies into LDS verbatim.
// ---------------------------------------------------------------------------
__global__ __launch_bounds__(256) void k_prep(const float* __restrict__ w2,
                                              const float* __restrict__ b2,
                                              ushort* __restrict__ w2t) {
    int s = blockIdx.x;                       // 0..64
    const float* src = (s < 64) ? (w2 + s * 4096) : b2;
    int t = threadIdx.x;
    int o = t >> 2;
    #pragma unroll
    for (int j = 0; j < 16; ++j) {
        int i = (t & 3) * 16 + j;
        w2t[s * 4096 + o * 64 + (i ^ ((o & 7) << 3))] = f2bf(src[i * 64 + o]);
    }
}

// ---------------------------------------------------------------------------
// agg init: agg[n][o] = xin[n][:] @ root + bias
// ---------------------------------------------------------------------------
__global__ __launch_bounds__(256) void k_agginit(const float* __restrict__ xin,
                                                 const float* __restrict__ root,
                                                 const float* __restrict__ bias,
                                                 float* __restrict__ agg) {
    int t = threadIdx.x;
    int o = t & 63;
    int n = blockIdx.x * 4 + (t >> 6);
    const float* xr = xin + n * DD;
    float acc = bias[o];
    #pragma unroll
    for (int i = 0; i < DD; ++i) acc += xr[i] * root[i * DD + o];
    agg[n * DD + o] = acc;
}

// ---------------------------------------------------------------------------
// conv (MFMA): block = 128 edges x 64 outputs, 4 waves x (M=32).
// A[e, s*64+i] = h[e,s] * xs[src[e], i]  built in registers;
// B = w2t slices streamed via global_load_lds, double-buffered.
// ---------------------------------------------------------------------------
__global__ __launch_bounds__(256) void k_conv(const float* __restrict__ xs,
                                              const __hip_bfloat16* __restrict__ het,
                                              const ushort* __restrict__ w2t,
                                              const int* __restrict__ ei,
                                              float* __restrict__ agg) {
    __shared__ __align__(16) ushort hs[65 * 128];     // h tile [k][e_local]
    __shared__ __align__(16) ushort w2s[2 * 4096];    // double-buffered B slice

    const int t   = threadIdx.x;
    const int l   = t & 63;
    const int w   = t >> 6;
    const int q   = l >> 4;                // lane quarter
    const int r16 = l & 15;
    const int q8  = q * 8;
    const int e0  = blockIdx.x * 128;

    // ---- xs fragments into registers: 2 sub-tiles x 16 cols ----
    float xsr[2][16];
    #pragma unroll
    for (int sm = 0; sm < 2; ++sm) {
        int em = e0 + w * 32 + sm * 16 + r16;
        int sn = ei[em];                                  // src node
        const float4* xr = (const float4*)(xs + sn * DD);
        float4 a0 = xr[q * 2], a1 = xr[q * 2 + 1];
        float4 b0 = xr[8 + q * 2], b1 = xr[8 + q * 2 + 1];
        xsr[sm][0] = a0.x;  xsr[sm][1] = a0.y;  xsr[sm][2]  = a0.z;  xsr[sm][3]  = a0.w;
        xsr[sm][4] = a1.x;  xsr[sm][5] = a1.y;  xsr[sm][6]  = a1.z;  xsr[sm][7]  = a1.w;
        xsr[sm][8] = b0.x;  xsr[sm][9] = b0.y;  xsr[sm][10] = b0.z;  xsr[sm][11] = b0.w;
        xsr[sm][12] = b1.x; xsr[sm][13] = b1.y; xsr[sm][14] = b1.z;  xsr[sm][15] = b1.w;
    }

    // ---- stage h tile [65][128] bf16 into LDS ----
    uint* hsu = (uint*)hs;
    for (int j = t; j < 65 * 64; j += 256) {
        int k = j >> 6, eu = j & 63;
        hsu[j] = ((const uint*)(het + k * EE + e0))[eu];
    }

    // drain everything before entering the counted-vmcnt regime
    asm volatile("s_waitcnt vmcnt(0) lgkmcnt(0)" ::: "memory");

    // B-fragment element offsets (swizzled), 2 K-steps x 4 N-tiles
    uint boff[2][4];
    #pragma unroll
    for (int nt = 0; nt < 4; ++nt) {
        int o = nt * 16 + r16;
        int x = (o & 7) << 3;
        #pragma unroll
        for (int p = 0; p < 2; ++p)
            boff[p][nt] = (uint)(o * 64 + ((p * 32 + q8) ^ x));
    }

    f32x4 acc[2][4];
    #pragma unroll
    for (int sm = 0; sm < 2; ++sm)
        #pragma unroll
        for (int nt = 0; nt < 4; ++nt)
            acc[sm][nt] = (f32x4){0.f, 0.f, 0.f, 0.f};

    auto stage = [&](int s) {
        #pragma unroll
        for (int c = 0; c < 2; ++c)
            gload_lds16(w2t + s * 4096 + w * 1024 + c * 512 + l * 8,
                        &w2s[(s & 1) * 4096 + w * 1024 + c * 512]);
    };

    stage(0);
    for (int s = 0; s < 65; ++s) {
        if (s < 64) {
            stage(s + 1);
            asm volatile("s_waitcnt vmcnt(2)" ::: "memory");   // slice s landed
        } else {
            asm volatile("s_waitcnt vmcnt(0)" ::: "memory");
        }
        __builtin_amdgcn_s_barrier();
        __builtin_amdgcn_sched_barrier(0);   // keep ds_reads below the barrier

        const ushort* bp = &w2s[(s & 1) * 4096];

        float hv[2];
        #pragma unroll
        for (int sm = 0; sm < 2; ++sm) {
            ushort hu = hs[s * 128 + w * 32 + sm * 16 + r16];
            union { uint u; float f; } cv; cv.u = ((uint)hu) << 16;
            hv[sm] = cv.f;
        }

        #pragma unroll
        for (int p = 0; p < 2; ++p) {
            bf16x8 bfr[4];
            #pragma unroll
            for (int nt = 0; nt < 4; ++nt)
                bfr[nt] = *(const bf16x8*)(bp + boff[p][nt]);
            #pragma unroll
            for (int sm = 0; sm < 2; ++sm) {
                union { bf16x8 v; ushort u[8]; } af;
                #pragma unroll
                for (int j = 0; j < 8; ++j)
                    af.u[j] = f2bf(hv[sm] * xsr[sm][p * 8 + j]);
                #pragma unroll
                for (int nt = 0; nt < 4; ++nt)
                    acc[sm][nt] = __builtin_amdgcn_mfma_f32_16x16x32_bf16(
                        af.v, bfr[nt], acc[sm][nt], 0, 0, 0);
            }
        }
        asm volatile("s_waitcnt lgkmcnt(0)" ::: "memory");     // reads done
        __builtin_amdgcn_s_barrier();                          // before overwrite
    }

    // ---- epilogue: C layout col=l&15, row=(l>>4)*4+r ----
    #pragma unroll
    for (int sm = 0; sm < 2; ++sm) {
        #pragma unroll
        for (int rr = 0; rr < 4; ++rr) {
            int em = e0 + w * 32 + sm * 16 + q * 4 + rr;
            int dn = ei[EE + em];                              // dst node
            float* ar = agg + dn * DD + r16;
            #pragma unroll
            for (int nt = 0; nt < 4; ++nt)
                atomicAdd(ar + nt * 16, acc[sm][nt][rr]);
        }
    }
}

// ---------------------------------------------------------------------------
// LN reduce: global sum / sum-of-squares
// ---------------------------------------------------------------------------
__global__ __launch_bounds__(256) void k_lnred(const float* __restrict__ v,
                                               float* __restrict__ stats) {
    int t = threadIdx.x;
    int base = blockIdx.x * 4096 + t;
    float s = 0.0f, s2 = 0.0f;
    #pragma unroll
    for (int j = 0; j < 16; ++j) {
        float x = v[base + j * 256];
        s += x; s2 += x * x;
    }
    #pragma unroll
    for (int off = 32; off > 0; off >>= 1) {
        s  += __shfl_down(s, off, 64);
        s2 += __shfl_down(s2, off, 64);
    }
    __shared__ float ps[8];
    int w = t >> 6;
    if ((t & 63) == 0) { ps[w] = s; ps[4 + w] = s2; }
    __syncthreads();
    if (t == 0) {
        atomicAdd(&stats[0], ps[0] + ps[1] + ps[2] + ps[3]);
        atomicAdd(&stats[1], ps[4] + ps[5] + ps[6] + ps[7]);
    }
}

// ---------------------------------------------------------------------------
// LN apply + relu (in place); reference divides by (std + eps)
// ---------------------------------------------------------------------------
__global__ __launch_bounds__(256) void k_lnapply(float* __restrict__ v,
                                                 const float* __restrict__ stats,
                                                 const float* __restrict__ gw,
                                                 const float* __restrict__ gb) {
    const float M = (float)(NN * DD);
    float mean = stats[0] / M;
    float var  = stats[1] / M - mean * mean;
    float rden = 1.0f / (sqrtf(fmaxf(var, 0.0f)) + EPSL);
    int t = threadIdx.x;
    int base = blockIdx.x * 1024 + t;
    #pragma unroll
    for (int j = 0; j < 4; ++j) {
        int idx = base + j * 256;
        int d = idx & 63;
        float x = v[idx];
        v[idx] = fmaxf((x - mean) * rden * gw[d] + gb[d], 0.0f);
    }
}

// ---------------------------------------------------------------------------
// pool: segment-sum by sorted batch, run-compressed atomics
// ---------------------------------------------------------------------------
__global__ __launch_bounds__(256) void k_pool(const float* __restrict__ h,
                                              const int* __restrict__ batch,
                                              float* __restrict__ pool,
                                              float* __restrict__ cnt) {
    int t = threadIdx.x;
    int d = t & 63;
    int ln = t >> 6;
    int n0 = blockIdx.x * 256;
    float s = 0.0f, sc = 0.0f;
    int cur = batch[n0 + ln];
    for (int j = 0; j < 64; ++j) {
        int n = n0 + ln + j * 4;
        int b = batch[n];
        if (b != cur) {
            atomicAdd(&pool[cur * DD + d], s);
            if (d == 0) atomicAdd(&cnt[cur], sc);
            s = 0.0f; sc = 0.0f; cur = b;
        }
        s  += h[n * DD + d];
        sc += 1.0f;
    }
    atomicAdd(&pool[cur * DD + d], s);
    if (d == 0) atomicAdd(&cnt[cur], sc);
}

// ---------------------------------------------------------------------------
// fc2
// ---------------------------------------------------------------------------
__global__ __launch_bounds__(256) void k_fc2(const float* __restrict__ pool,
                                             const float* __restrict__ cnt,
                                             const float* __restrict__ w,
                                             const float* __restrict__ b,
                                             float* __restrict__ out) {
    int t = threadIdx.x;
    int o = t & 15;
    int g0 = t >> 4;
    #pragma unroll
    for (int gg = 0; gg < 4; ++gg) {
        int g = g0 + gg * 16;
        float inv = 1.0f / fmaxf(cnt[g], 1.0f);
        float acc = b[o];
        for (int d = 0; d < DD; ++d)
            acc += pool[g * DD + d] * inv * w[d * OUTD + o];
        out[g * OUTD + o] = acc;
    }
}

// ---------------------------------------------------------------------------
extern "C" void kernel_launch(void* const* d_in, const int* in_sizes, int n_in,
                              void* d_out, int out_size, void* d_ws, size_t ws_size,
                              hipStream_t stream) {
    const float* x       = (const float*)d_in[0];
    const float* ea      = (const float*)d_in[1];
    const int*   ei      = (const int*)d_in[2];
    const int*   batch   = (const int*)d_in[3];
    const float* fc1_w   = (const float*)d_in[4];
    const float* fc1_b   = (const float*)d_in[5];
    const float* e1w1    = (const float*)d_in[6];
    const float* e1b1    = (const float*)d_in[7];
    const float* e1w2    = (const float*)d_in[8];
    const float* e1b2    = (const float*)d_in[9];
    const float* root1   = (const float*)d_in[10];
    const float* bias1   = (const float*)d_in[11];
    const float* gn1w    = (const float*)d_in[12];
    const float* gn1b    = (const float*)d_in[13];
    const float* e2w1    = (const float*)d_in[14];
    const float* e2b1    = (const float*)d_in[15];
    const float* e2w2    = (const float*)d_in[16];
    const float* e2b2    = (const float*)d_in[17];
    const float* root2   = (const float*)d_in[18];
    const float* bias2   = (const float*)d_in[19];
    const float* gn2w    = (const float*)d_in[20];
    const float* gn2b    = (const float*)d_in[21];
    const float* fc2_w   = (const float*)d_in[22];
    const float* fc2_b   = (const float*)d_in[23];
    float* out = (float*)d_out;

    // workspace layout (bytes)
    char* ws = (char*)d_ws;
    float*          hx    = (float*)(ws);                      // 8 MB, reused as agg2
    float*          agg1  = (float*)(ws + 8388608);            // 8 MB
    __hip_bfloat16* het   = (__hip_bfloat16*)(ws + 16777216);  // 65*E bf16 = 12.78 MB
    ushort*         w2t   = (ushort*)(ws + 29556736);          // 65*4096*2 = 520 KB
    float*          pool  = (float*)(ws + 30089216);           // 16 KB
    float*          cnt   = (float*)(ws + 30105600);           // 256 B
    float*          stats = (float*)(ws + 30105856);           // 16 B
    float*          agg2  = hx;

    hipMemsetAsync(ws + 30089216, 0, 16384 + 256 + 16, stream);

    // ---- layer 1 ----
    k_fc1<<<NN / 4, 256, 0, stream>>>(x, fc1_w, fc1_b, hx);
    k_mlp<<<EE / 256, 256, 0, stream>>>(ea, e1w1, e1b1, het);
    k_prep<<<65, 256, 0, stream>>>(e1w2, e1b2, w2t);
    k_agginit<<<NN / 4, 256, 0, stream>>>(hx, root1, bias1, agg1);
    k_conv<<<EE / 128, 256, 0, stream>>>(hx, het, w2t, ei, agg1);
    k_lnred<<<(NN * DD) / 4096, 256, 0, stream>>>(agg1, stats);
    k_lnapply<<<(NN * DD) / 1024, 256, 0, stream>>>(agg1, stats, gn1w, gn1b);

    // ---- layer 2 ----
    k_mlp<<<EE / 256, 256, 0, stream>>>(ea, e2w1, e2b1, het);
    k_prep<<<65, 256, 0, stream>>>(e2w2, e2b2, w2t);
    k_agginit<<<NN / 4, 256, 0, stream>>>(agg1, root2, bias2, agg2);
    k_conv<<<EE / 128, 256, 0, stream>>>(agg1, het, w2t, ei, agg2);
    k_lnred<<<(NN * DD) / 4096, 256, 0, stream>>>(agg2, stats + 2);
    k_lnapply<<<(NN * DD) / 1024, 256, 0, stream>>>(agg2, stats + 2, gn2w, gn2b);

    // ---- pool + fc2 ----
    k_pool<<<NN / 256, 256, 0, stream>>>(agg2, batch, pool, cnt);
    k_fc2<<<1, 256, 0, stream>>>(pool, cnt, fc2_w, fc2_b, out);
}

// Round 3
// 422.280 us; speedup vs baseline: 5.3559x; 1.0517x over previous
//
#include <hip/hip_runtime.h>
#include <hip/hip_bf16.h>
#include <hip/hip_fp16.h>

// Problem constants
#define NN    32768
#define EE    98304
#define FN    32
#define FEDGE 16
#define DD    64
#define OUTD  16
#define GG    64
#define EPSL  1e-5f
#define EB    384      // edges per conv block

typedef __attribute__((ext_vector_type(8))) _Float16 f16x8;
typedef __attribute__((ext_vector_type(4))) float f32x4;

__device__ __forceinline__ void gload_lds16(const void* g, void* l) {
    __builtin_amdgcn_global_load_lds(
        (const __attribute__((address_space(1))) void*)g,
        (__attribute__((address_space(3))) void*)l, 16, 0, 0);
}

// ---------------------------------------------------------------------------
// fc1 + agginit1 fused: hx = x@fc1_w+fc1_b ; agg1 = hx@root1 + bias1
// wave = one node (64 d-lanes); row shared via LDS broadcast
// ---------------------------------------------------------------------------
__global__ __launch_bounds__(256) void k_fc1agg(const float* __restrict__ x,
                                                const float* __restrict__ w1,
                                                const float* __restrict__ b1,
                                                const float* __restrict__ root,
                                                const float* __restrict__ rbias,
                                                float* __restrict__ hx,
                                                float* __restrict__ agg) {
    __shared__ float rowbuf[4][64];
    int t = threadIdx.x, d = t & 63, wv = t >> 6;
    int n = blockIdx.x * 4 + wv;
    const float* xr = x + n * FN;
    float acc = b1[d];
    #pragma unroll
    for (int i = 0; i < FN; ++i) acc += xr[i] * w1[i * DD + d];
    hx[n * DD + d] = acc;
    rowbuf[wv][d] = acc;
    __syncthreads();
    float a0 = rbias[d], a1 = 0.f, a2 = 0.f, a3 = 0.f;
    #pragma unroll
    for (int i = 0; i < DD; i += 4) {
        a0 += rowbuf[wv][i]     * root[i * DD + d];
        a1 += rowbuf[wv][i + 1] * root[(i + 1) * DD + d];
        a2 += rowbuf[wv][i + 2] * root[(i + 2) * DD + d];
        a3 += rowbuf[wv][i + 3] * root[(i + 3) * DD + d];
    }
    agg[n * DD + d] = (a0 + a1) + (a2 + a3);
}

// ---------------------------------------------------------------------------
// edge MLP: het[k][e] = relu(ea[e][:16] @ w1 + b1) (fp16),  het[64][e] = 1.0
// ---------------------------------------------------------------------------
__global__ __launch_bounds__(256) void k_mlp(const float* __restrict__ ea,
                                             const float* __restrict__ w1,
                                             const float* __restrict__ b1,
                                             __half* __restrict__ het) {
    __shared__ float eas[256][17];
    int t = threadIdx.x;
    int e0 = blockIdx.x * 256;
    const float4* src = (const float4*)(ea + e0 * FEDGE);
    #pragma unroll
    for (int j = 0; j < 4; ++j) {
        float4 v = src[t + 256 * j];
        int f = (t + 256 * j) * 4;
        int e = f >> 4, i = f & 15;
        eas[e][i] = v.x; eas[e][i + 1] = v.y; eas[e][i + 2] = v.z; eas[e][i + 3] = v.w;
    }
    __syncthreads();
    int e = e0 + t;
    float a[FEDGE];
    #pragma unroll
    for (int i = 0; i < FEDGE; ++i) a[i] = eas[t][i];
    for (int k = 0; k < DD; ++k) {
        float acc = b1[k];
        #pragma unroll
        for (int i = 0; i < FEDGE; ++i) acc += a[i] * w1[i * DD + k];
        acc = fmaxf(acc, 0.0f);
        het[k * EE + e] = __float2half_rn(acc);
    }
    het[DD * EE + e] = __float2half_rn(1.0f);
}

// ---------------------------------------------------------------------------
// prep: w2t[s][o][i^((o&7)<<3)] = fp16(slice_s[i][o]);  slice 64 = b2.
// ---------------------------------------------------------------------------
__global__ __launch_bounds__(256) void k_prep(const float* __restrict__ w2,
                                              const float* __restrict__ b2,
                                              __half* __restrict__ w2t) {
    int s = blockIdx.x;                       // 0..64
    const float* src = (s < 64) ? (w2 + s * 4096) : b2;
    int t = threadIdx.x;
    int o = t >> 2;
    #pragma unroll
    for (int j = 0; j < 16; ++j) {
        int i = (t & 3) * 16 + j;
        w2t[s * 4096 + o * 64 + (i ^ ((o & 7) << 3))] = __float2half_rn(src[i * 64 + o]);
    }
}

// ---------------------------------------------------------------------------
// conv (MFMA f16): block = 384 edges x 64 outputs, 4 waves x (M=96).
// grid = EE/384 = 256 blocks -> exactly 1 block per CU (balanced).
// A[e, s*64+i] = h[e,s]*xs[src[e],i] built in regs via v_pk_mul_f16;
// B = w2t slices streamed via global_load_lds, double-buffered, vmcnt-counted.
// ---------------------------------------------------------------------------
__global__ __launch_bounds__(256, 1) void k_conv(const float* __restrict__ xs,
                                                 const __half* __restrict__ het,
                                                 const __half* __restrict__ w2t,
                                                 const int* __restrict__ ei,
                                                 float* __restrict__ agg) {
    __shared__ __align__(16) __half hs[65 * EB];      // h tile [s][e_local] 49.9 KB
    __shared__ __align__(16) __half w2s[2 * 4096];    // dbuf B slice 16.4 KB

    const int t   = threadIdx.x;
    const int l   = t & 63;
    const int w   = t >> 6;
    const int q   = l >> 4;
    const int r16 = l & 15;
    const int q8  = q * 8;
    const int e0  = blockIdx.x * EB;

    // ---- xs fragments -> fp16 registers: 6 sub-tiles x 16 k-vals ----
    __half2 xh[6][8];
    #pragma unroll
    for (int sm = 0; sm < 6; ++sm) {
        int em = e0 + w * 96 + sm * 16 + r16;
        int sn = ei[em];                              // src node
        const float4* xr = (const float4*)(xs + sn * DD);
        float4 a0 = xr[q * 2], a1 = xr[q * 2 + 1];
        float4 b0 = xr[8 + q * 2], b1 = xr[8 + q * 2 + 1];
        xh[sm][0] = __floats2half2_rn(a0.x, a0.y);
        xh[sm][1] = __floats2half2_rn(a0.z, a0.w);
        xh[sm][2] = __floats2half2_rn(a1.x, a1.y);
        xh[sm][3] = __floats2half2_rn(a1.z, a1.w);
        xh[sm][4] = __floats2half2_rn(b0.x, b0.y);
        xh[sm][5] = __floats2half2_rn(b0.z, b0.w);
        xh[sm][6] = __floats2half2_rn(b1.x, b1.y);
        xh[sm][7] = __floats2half2_rn(b1.z, b1.w);
    }

    // ---- stage h tile [65][EB] fp16 into LDS (65 rows x 48 uint4) ----
    for (int j = t; j < 65 * 48; j += 256) {
        int row = j / 48, col = j - row * 48;
        ((uint4*)hs)[j] = ((const uint4*)(het + row * EE + e0))[col];
    }

    // B-fragment element offsets (swizzled), 2 K-halves x 4 N-tiles
    uint boff[2][4];
    #pragma unroll
    for (int nt = 0; nt < 4; ++nt) {
        int o = nt * 16 + r16;
        int xm = (o & 7) << 3;
        #pragma unroll
        for (int p = 0; p < 2; ++p)
            boff[p][nt] = (uint)(o * 64 + ((p * 32 + q8) ^ xm));
    }

    f32x4 acc[6][4];
    #pragma unroll
    for (int sm = 0; sm < 6; ++sm)
        #pragma unroll
        for (int nt = 0; nt < 4; ++nt)
            acc[sm][nt] = (f32x4){0.f, 0.f, 0.f, 0.f};

    auto stage = [&](int s) {
        #pragma unroll
        for (int c = 0; c < 2; ++c)
            gload_lds16(w2t + s * 4096 + w * 1024 + c * 512 + l * 8,
                        &w2s[(s & 1) * 4096 + w * 1024 + c * 512]);
    };

    stage(0);
    asm volatile("s_waitcnt vmcnt(0) lgkmcnt(0)" ::: "memory");

    for (int s = 0; s < 65; ++s) {
        if (s < 64) {
            stage(s + 1);
            asm volatile("s_waitcnt vmcnt(2)" ::: "memory");   // slice s landed
        } else {
            asm volatile("s_waitcnt vmcnt(0)" ::: "memory");
        }
        __builtin_amdgcn_s_barrier();
        __builtin_amdgcn_sched_barrier(0);

        const __half* bp = &w2s[(s & 1) * 4096];

        __half2 hh[6];
        #pragma unroll
        for (int sm = 0; sm < 6; ++sm)
            hh[sm] = __half2half2(hs[s * EB + w * 96 + sm * 16 + r16]);

        #pragma unroll
        for (int p = 0; p < 2; ++p) {
            f16x8 bfr[4];
            #pragma unroll
            for (int nt = 0; nt < 4; ++nt)
                bfr[nt] = *(const f16x8*)(bp + boff[p][nt]);
            #pragma unroll
            for (int sm = 0; sm < 6; ++sm) {
                union { f16x8 v; __half2 h2[4]; } af;
                #pragma unroll
                for (int jj = 0; jj < 4; ++jj)
                    af.h2[jj] = __hmul2(hh[sm], xh[sm][p * 4 + jj]);
                #pragma unroll
                for (int nt = 0; nt < 4; ++nt)
                    acc[sm][nt] = __builtin_amdgcn_mfma_f32_16x16x32_f16(
                        af.v, bfr[nt], acc[sm][nt], 0, 0, 0);
            }
        }
        asm volatile("s_waitcnt lgkmcnt(0)" ::: "memory");     // LDS reads done
        __builtin_amdgcn_s_barrier();                          // before overwrite
    }

    // ---- epilogue: C layout col=r16, row=q*4+rr ----
    #pragma unroll
    for (int sm = 0; sm < 6; ++sm) {
        #pragma unroll
        for (int rr = 0; rr < 4; ++rr) {
            int em = e0 + w * 96 + sm * 16 + q * 4 + rr;
            int dn = ei[EE + em];                              // dst node
            float* ar = agg + dn * DD + r16;
            #pragma unroll
            for (int nt = 0; nt < 4; ++nt)
                atomicAdd(ar + nt * 16, acc[sm][nt][rr]);
        }
    }
}

// ---------------------------------------------------------------------------
// LN reduce: global sum / sum-of-squares
// ---------------------------------------------------------------------------
__global__ __launch_bounds__(256) void k_lnred(const float* __restrict__ v,
                                               float* __restrict__ stats) {
    int t = threadIdx.x;
    int base = blockIdx.x * 4096 + t;
    float s = 0.0f, s2 = 0.0f;
    #pragma unroll
    for (int j = 0; j < 16; ++j) {
        float x = v[base + j * 256];
        s += x; s2 += x * x;
    }
    #pragma unroll
    for (int off = 32; off > 0; off >>= 1) {
        s  += __shfl_down(s, off, 64);
        s2 += __shfl_down(s2, off, 64);
    }
    __shared__ float ps[8];
    int w = t >> 6;
    if ((t & 63) == 0) { ps[w] = s; ps[4 + w] = s2; }
    __syncthreads();
    if (t == 0) {
        atomicAdd(&stats[0], ps[0] + ps[1] + ps[2] + ps[3]);
        atomicAdd(&stats[1], ps[4] + ps[5] + ps[6] + ps[7]);
    }
}

// ---------------------------------------------------------------------------
// lnapply1 + agginit2 fused: h1 = relu(norm(agg1raw)) in place;
// agg2 = h1@root2 + bias2.  (reference divides by (std + eps))
// ---------------------------------------------------------------------------
__global__ __launch_bounds__(256) void k_lnagg(float* __restrict__ h1,
                                               const float* __restrict__ stats,
                                               const float* __restrict__ gw,
                                               const float* __restrict__ gb,
                                               const float* __restrict__ root,
                                               const float* __restrict__ rbias,
                                               float* __restrict__ agg2) {
    const float M = (float)(NN * DD);
    float mean = stats[0] / M;
    float var  = stats[1] / M - mean * mean;
    float rden = 1.0f / (sqrtf(fmaxf(var, 0.0f)) + EPSL);
    __shared__ float rowbuf[4][64];
    int t = threadIdx.x, d = t & 63, wv = t >> 6;
    int n = blockIdx.x * 4 + wv;
    float v = h1[n * DD + d];
    float h = fmaxf((v - mean) * rden * gw[d] + gb[d], 0.0f);
    h1[n * DD + d] = h;
    rowbuf[wv][d] = h;
    __syncthreads();
    float a0 = rbias[d], a1 = 0.f, a2 = 0.f, a3 = 0.f;
    #pragma unroll
    for (int i = 0; i < DD; i += 4) {
        a0 += rowbuf[wv][i]     * root[i * DD + d];
        a1 += rowbuf[wv][i + 1] * root[(i + 1) * DD + d];
        a2 += rowbuf[wv][i + 2] * root[(i + 2) * DD + d];
        a3 += rowbuf[wv][i + 3] * root[(i + 3) * DD + d];
    }
    agg2[n * DD + d] = (a0 + a1) + (a2 + a3);
}

// ---------------------------------------------------------------------------
// lnapply2 + pool fused: normalize agg2raw on the fly, segment-sum by batch
// ---------------------------------------------------------------------------
__global__ __launch_bounds__(256) void k_lnpool(const float* __restrict__ v,
                                                const float* __restrict__ stats,
                                                const float* __restrict__ gw,
                                                const float* __restrict__ gb,
                                                const int* __restrict__ batch,
                                                float* __restrict__ pool,
                                                float* __restrict__ cnt) {
    const float M = (float)(NN * DD);
    float mean = stats[0] / M;
    float var  = stats[1] / M - mean * mean;
    float rden = 1.0f / (sqrtf(fmaxf(var, 0.0f)) + EPSL);
    int t = threadIdx.x;
    int d = t & 63;
    int ln = t >> 6;
    int n0 = blockIdx.x * 256;
    float gwd = gw[d] * rden, gbd = gb[d];
    float s = 0.0f, sc = 0.0f;
    int cur = batch[n0 + ln];
    for (int j = 0; j < 64; ++j) {
        int n = n0 + ln + j * 4;
        int b = batch[n];
        if (b != cur) {
            atomicAdd(&pool[cur * DD + d], s);
            if (d == 0) atomicAdd(&cnt[cur], sc);
            s = 0.0f; sc = 0.0f; cur = b;
        }
        s  += fmaxf((v[n * DD + d] - mean) * gwd + gbd, 0.0f);
        sc += 1.0f;
    }
    atomicAdd(&pool[cur * DD + d], s);
    if (d == 0) atomicAdd(&cnt[cur], sc);
}

// ---------------------------------------------------------------------------
// fc2
// ---------------------------------------------------------------------------
__global__ __launch_bounds__(256) void k_fc2(const float* __restrict__ pool,
                                             const float* __restrict__ cnt,
                                             const float* __restrict__ w,
                                             const float* __restrict__ b,
                                             float* __restrict__ out) {
    int t = threadIdx.x;
    int o = t & 15;
    int g0 = t >> 4;
    #pragma unroll
    for (int gg = 0; gg < 4; ++gg) {
        int g = g0 + gg * 16;
        float inv = 1.0f / fmaxf(cnt[g], 1.0f);
        float acc = b[o];
        for (int d = 0; d < DD; ++d)
            acc += pool[g * DD + d] * inv * w[d * OUTD + o];
        out[g * OUTD + o] = acc;
    }
}

// ---------------------------------------------------------------------------
extern "C" void kernel_launch(void* const* d_in, const int* in_sizes, int n_in,
                              void* d_out, int out_size, void* d_ws, size_t ws_size,
                              hipStream_t stream) {
    const float* x       = (const float*)d_in[0];
    const float* ea      = (const float*)d_in[1];
    const int*   ei      = (const int*)d_in[2];
    const int*   batch   = (const int*)d_in[3];
    const float* fc1_w   = (const float*)d_in[4];
    const float* fc1_b   = (const float*)d_in[5];
    const float* e1w1    = (const float*)d_in[6];
    const float* e1b1    = (const float*)d_in[7];
    const float* e1w2    = (const float*)d_in[8];
    const float* e1b2    = (const float*)d_in[9];
    const float* root1   = (const float*)d_in[10];
    const float* bias1   = (const float*)d_in[11];
    const float* gn1w    = (const float*)d_in[12];
    const float* gn1b    = (const float*)d_in[13];
    const float* e2w1    = (const float*)d_in[14];
    const float* e2b1    = (const float*)d_in[15];
    const float* e2w2    = (const float*)d_in[16];
    const float* e2b2    = (const float*)d_in[17];
    const float* root2   = (const float*)d_in[18];
    const float* bias2   = (const float*)d_in[19];
    const float* gn2w    = (const float*)d_in[20];
    const float* gn2b    = (const float*)d_in[21];
    const float* fc2_w   = (const float*)d_in[22];
    const float* fc2_b   = (const float*)d_in[23];
    float* out = (float*)d_out;

    // workspace layout (bytes)
    char* ws = (char*)d_ws;
    float*  hx    = (float*)(ws);                      // 8 MB; reused as agg2
    float*  agg1  = (float*)(ws + 8388608);            // 8 MB; becomes h1 in place
    __half* het   = (__half*)(ws + 16777216);          // 65*E fp16 = 12.78 MB
    __half* w2t   = (__half*)(ws + 29556736);          // 65*4096 fp16 = 520 KB
    float*  pool  = (float*)(ws + 30089216);           // 16 KB
    float*  cnt   = (float*)(ws + 30105600);           // 256 B
    float*  stats = (float*)(ws + 30105856);           // 16 B
    float*  agg2  = hx;

    hipMemsetAsync(ws + 30089216, 0, 16384 + 256 + 16, stream);

    // ---- layer 1 ----
    k_fc1agg<<<NN / 4, 256, 0, stream>>>(x, fc1_w, fc1_b, root1, bias1, hx, agg1);
    k_mlp<<<EE / 256, 256, 0, stream>>>(ea, e1w1, e1b1, het);
    k_prep<<<65, 256, 0, stream>>>(e1w2, e1b2, w2t);
    k_conv<<<EE / EB, 256, 0, stream>>>(hx, het, w2t, ei, agg1);
    k_lnred<<<(NN * DD) / 4096, 256, 0, stream>>>(agg1, stats);
    k_lnagg<<<NN / 4, 256, 0, stream>>>(agg1, stats, gn1w, gn1b, root2, bias2, agg2);

    // ---- layer 2 ----  (h1 == agg1 in place; agg2 reuses hx buffer)
    k_mlp<<<EE / 256, 256, 0, stream>>>(ea, e2w1, e2b1, het);
    k_prep<<<65, 256, 0, stream>>>(e2w2, e2b2, w2t);
    k_conv<<<EE / EB, 256, 0, stream>>>(agg1, het, w2t, ei, agg2);
    k_lnred<<<(NN * DD) / 4096, 256, 0, stream>>>(agg2, stats + 2);

    // ---- pool (fused with lnapply2) + fc2 ----
    k_lnpool<<<NN / 256, 256, 0, stream>>>(agg2, stats + 2, gn2w, gn2b, batch, pool, cnt);
    k_fc2<<<1, 256, 0, stream>>>(pool, cnt, fc2_w, fc2_b, out);
}

// Round 4
// 386.031 us; speedup vs baseline: 5.8588x; 1.0939x over previous
//
#include <hip/hip_runtime.h>
#include <hip/hip_bf16.h>
#include <hip/hip_fp16.h>

// Problem constants
#define NN    32768
#define EE    98304
#define FN    32
#define FEDGE 16
#define DD    64
#define OUTD  16
#define GG    64
#define EPSL  1e-5f
#define EB    192      // edges per conv block

typedef __attribute__((ext_vector_type(8))) _Float16 f16x8;
typedef __attribute__((ext_vector_type(4))) float f32x4;

__device__ __forceinline__ void gload_lds16(const void* g, void* l) {
    __builtin_amdgcn_global_load_lds(
        (const __attribute__((address_space(1))) void*)g,
        (__attribute__((address_space(3))) void*)l, 16, 0, 0);
}

// ---------------------------------------------------------------------------
// fc1 + agginit1 fused: hx = x@fc1_w+fc1_b ; agg1 = hx@root1 + bias1
// ---------------------------------------------------------------------------
__global__ __launch_bounds__(256) void k_fc1agg(const float* __restrict__ x,
                                                const float* __restrict__ w1,
                                                const float* __restrict__ b1,
                                                const float* __restrict__ root,
                                                const float* __restrict__ rbias,
                                                float* __restrict__ hx,
                                                float* __restrict__ agg) {
    __shared__ float rowbuf[4][64];
    int t = threadIdx.x, d = t & 63, wv = t >> 6;
    int n = blockIdx.x * 4 + wv;
    const float* xr = x + n * FN;
    float acc = b1[d];
    #pragma unroll
    for (int i = 0; i < FN; ++i) acc += xr[i] * w1[i * DD + d];
    hx[n * DD + d] = acc;
    rowbuf[wv][d] = acc;
    __syncthreads();
    float a0 = rbias[d], a1 = 0.f, a2 = 0.f, a3 = 0.f;
    #pragma unroll
    for (int i = 0; i < DD; i += 4) {
        a0 += rowbuf[wv][i]     * root[i * DD + d];
        a1 += rowbuf[wv][i + 1] * root[(i + 1) * DD + d];
        a2 += rowbuf[wv][i + 2] * root[(i + 2) * DD + d];
        a3 += rowbuf[wv][i + 3] * root[(i + 3) * DD + d];
    }
    agg[n * DD + d] = (a0 + a1) + (a2 + a3);
}

// ---------------------------------------------------------------------------
// edge MLP (+ fused w2 prep on blocks 0..64):
//   het[k][e] = relu(ea[e][:16] @ w1 + b1) (fp16),  het[64][e] = 1.0
//   w2t[s][o][i^((o&7)<<3)] = fp16(slice_s[i][o]);  slice 64 = b2.
// ---------------------------------------------------------------------------
__global__ __launch_bounds__(256) void k_mlpprep(const float* __restrict__ ea,
                                                 const float* __restrict__ w1,
                                                 const float* __restrict__ b1,
                                                 __half* __restrict__ het,
                                                 const float* __restrict__ w2,
                                                 const float* __restrict__ b2,
                                                 __half* __restrict__ w2t) {
    __shared__ float eas[256][17];
    int t = threadIdx.x;
    int e0 = blockIdx.x * 256;
    const float4* src = (const float4*)(ea + e0 * FEDGE);
    #pragma unroll
    for (int j = 0; j < 4; ++j) {
        float4 v = src[t + 256 * j];
        int f = (t + 256 * j) * 4;
        int e = f >> 4, i = f & 15;
        eas[e][i] = v.x; eas[e][i + 1] = v.y; eas[e][i + 2] = v.z; eas[e][i + 3] = v.w;
    }
    // fused prep (65 of the 384 blocks)
    if (blockIdx.x < 65) {
        int s = blockIdx.x;
        const float* psrc = (s < 64) ? (w2 + s * 4096) : b2;
        int o = t >> 2;
        #pragma unroll
        for (int j = 0; j < 16; ++j) {
            int i = (t & 3) * 16 + j;
            w2t[s * 4096 + o * 64 + (i ^ ((o & 7) << 3))] = __float2half_rn(psrc[i * 64 + o]);
        }
    }
    __syncthreads();
    int e = e0 + t;
    float a[FEDGE];
    #pragma unroll
    for (int i = 0; i < FEDGE; ++i) a[i] = eas[t][i];
    for (int k = 0; k < DD; ++k) {
        float acc = b1[k];
        #pragma unroll
        for (int i = 0; i < FEDGE; ++i) acc += a[i] * w1[i * DD + k];
        acc = fmaxf(acc, 0.0f);
        het[k * EE + e] = __float2half_rn(acc);
    }
    het[DD * EE + e] = __float2half_rn(1.0f);
}

// ---------------------------------------------------------------------------
// conv (MFMA f16): block = 192 edges x 64 outputs, grid = 512 = 2 blocks/CU.
// 4 waves as 2x2 (wm = edge-half, wn = output-half):
//   wave handles 6 M-sub-tiles x 2 N-tiles; 24 MFMA/slice.
// B = w2t slices in a 4-deep LDS ring, 3-deep prefetch, counted vmcnt(6).
// Block 0 additionally zeroes `zbuf[0..zn)` (stats/pool/cnt init).
// ---------------------------------------------------------------------------
__global__ __launch_bounds__(256, 2) void k_conv(const float* __restrict__ xs,
                                                 const __half* __restrict__ het,
                                                 const __half* __restrict__ w2t,
                                                 const int* __restrict__ ei,
                                                 float* __restrict__ agg,
                                                 float* __restrict__ zbuf,
                                                 int zn) {
    __shared__ __align__(16) __half hs[65 * EB];      // 24.96 KB
    __shared__ __align__(16) __half w2s[4 * 4096];    // 32.77 KB ring

    const int t   = threadIdx.x;
    const int l   = t & 63;
    const int w   = t >> 6;
    const int wm  = w & 1;                 // edge half (0/1)
    const int wn  = w >> 1;                // output half (0/1)
    const int q   = l >> 4;
    const int r16 = l & 15;
    const int q8  = q * 8;
    const int e0  = blockIdx.x * EB;

    if (blockIdx.x == 0) {
        for (int i = t; i < zn; i += 256) zbuf[i] = 0.0f;
    }

    // ---- xs fragments -> fp16 registers: 6 sub-tiles x 16 k-vals ----
    __half2 xh[6][8];
    #pragma unroll
    for (int sm = 0; sm < 6; ++sm) {
        int em = e0 + wm * 96 + sm * 16 + r16;
        int sn = ei[em];                              // src node
        const float4* xr = (const float4*)(xs + sn * DD);
        float4 a0 = xr[q * 2], a1 = xr[q * 2 + 1];
        float4 b0 = xr[8 + q * 2], b1 = xr[8 + q * 2 + 1];
        xh[sm][0] = __floats2half2_rn(a0.x, a0.y);
        xh[sm][1] = __floats2half2_rn(a0.z, a0.w);
        xh[sm][2] = __floats2half2_rn(a1.x, a1.y);
        xh[sm][3] = __floats2half2_rn(a1.z, a1.w);
        xh[sm][4] = __floats2half2_rn(b0.x, b0.y);
        xh[sm][5] = __floats2half2_rn(b0.z, b0.w);
        xh[sm][6] = __floats2half2_rn(b1.x, b1.y);
        xh[sm][7] = __floats2half2_rn(b1.z, b1.w);
    }

    auto stage = [&](int s) {
        #pragma unroll
        for (int c = 0; c < 2; ++c)
            gload_lds16(w2t + s * 4096 + w * 1024 + c * 512 + l * 8,
                        &w2s[(s & 3) * 4096 + w * 1024 + c * 512]);
    };

    // prefetch slices 0..2 BEFORE hs staging (so loop-entry vmcnt count = 6)
    stage(0); stage(1); stage(2);

    // ---- stage h tile [65][EB] fp16 into LDS (65 rows x 24 uint4) ----
    for (int j = t; j < 65 * 24; j += 256) {
        int row = j / 24, col = j - row * 24;
        ((uint4*)hs)[j] = ((const uint4*)(het + row * EE + e0))[col];
    }
    asm volatile("s_waitcnt lgkmcnt(0)" ::: "memory");   // hs writes committed

    // B-fragment element offsets (swizzled), 2 K-halves x 2 N-tiles
    uint boff[2][2];
    #pragma unroll
    for (int j = 0; j < 2; ++j) {
        int o = (wn * 2 + j) * 16 + r16;
        int xm = (o & 7) << 3;
        #pragma unroll
        for (int p = 0; p < 2; ++p)
            boff[p][j] = (uint)(o * 64 + ((p * 32 + q8) ^ xm));
    }

    f32x4 acc[6][2];
    #pragma unroll
    for (int sm = 0; sm < 6; ++sm)
        #pragma unroll
        for (int j = 0; j < 2; ++j)
            acc[sm][j] = (f32x4){0.f, 0.f, 0.f, 0.f};

    for (int s = 0; s < 65; ++s) {
        __builtin_amdgcn_s_barrier();            // all waves done with slice s-1
        if (s < 62) {
            stage(s + 3);                        // overwrites buf read at s-1: safe
            asm volatile("s_waitcnt vmcnt(6)" ::: "memory");   // own slice-s landed
        } else {
            asm volatile("s_waitcnt vmcnt(0)" ::: "memory");
        }
        __builtin_amdgcn_s_barrier();            // everyone's slice-s landed
        __builtin_amdgcn_sched_barrier(0);

        const __half* bp = &w2s[(s & 3) * 4096];

        __half2 hh[6];
        #pragma unroll
        for (int sm = 0; sm < 6; ++sm)
            hh[sm] = __half2half2(hs[s * EB + wm * 96 + sm * 16 + r16]);

        #pragma unroll
        for (int p = 0; p < 2; ++p) {
            f16x8 bfr[2];
            #pragma unroll
            for (int j = 0; j < 2; ++j)
                bfr[j] = *(const f16x8*)(bp + boff[p][j]);
            #pragma unroll
            for (int sm = 0; sm < 6; ++sm) {
                union { f16x8 v; __half2 h2[4]; } af;
                #pragma unroll
                for (int jj = 0; jj < 4; ++jj)
                    af.h2[jj] = __hmul2(hh[sm], xh[sm][p * 4 + jj]);
                #pragma unroll
                for (int j = 0; j < 2; ++j)
                    acc[sm][j] = __builtin_amdgcn_mfma_f32_16x16x32_f16(
                        af.v, bfr[j], acc[sm][j], 0, 0, 0);
            }
        }
    }

    // ---- epilogue: C layout col=r16, row=q*4+rr ----
    #pragma unroll
    for (int sm = 0; sm < 6; ++sm) {
        #pragma unroll
        for (int rr = 0; rr < 4; ++rr) {
            int em = e0 + wm * 96 + sm * 16 + q * 4 + rr;
            int dn = ei[EE + em];                              // dst node
            float* ar = agg + dn * DD + wn * 32 + r16;
            #pragma unroll
            for (int j = 0; j < 2; ++j)
                atomicAdd(ar + j * 16, acc[sm][j][rr]);
        }
    }
}

// ---------------------------------------------------------------------------
// LN reduce: global sum / sum-of-squares
// ---------------------------------------------------------------------------
__global__ __launch_bounds__(256) void k_lnred(const float* __restrict__ v,
                                               float* __restrict__ stats) {
    int t = threadIdx.x;
    int base = blockIdx.x * 4096 + t;
    float s = 0.0f, s2 = 0.0f;
    #pragma unroll
    for (int j = 0; j < 16; ++j) {
        float x = v[base + j * 256];
        s += x; s2 += x * x;
    }
    #pragma unroll
    for (int off = 32; off > 0; off >>= 1) {
        s  += __shfl_down(s, off, 64);
        s2 += __shfl_down(s2, off, 64);
    }
    __shared__ float ps[8];
    int w = t >> 6;
    if ((t & 63) == 0) { ps[w] = s; ps[4 + w] = s2; }
    __syncthreads();
    if (t == 0) {
        atomicAdd(&stats[0], ps[0] + ps[1] + ps[2] + ps[3]);
        atomicAdd(&stats[1], ps[4] + ps[5] + ps[6] + ps[7]);
    }
}

// ---------------------------------------------------------------------------
// lnapply1 + agginit2 fused: h1 = relu(norm(agg1raw)) in place;
// agg2 = h1@root2 + bias2.  (reference divides by (std + eps))
// ---------------------------------------------------------------------------
__global__ __launch_bounds__(256) void k_lnagg(float* __restrict__ h1,
                                               const float* __restrict__ stats,
                                               const float* __restrict__ gw,
                                               const float* __restrict__ gb,
                                               const float* __restrict__ root,
                                               const float* __restrict__ rbias,
                                               float* __restrict__ agg2) {
    const float M = (float)(NN * DD);
    float mean = stats[0] / M;
    float var  = stats[1] / M - mean * mean;
    float rden = 1.0f / (sqrtf(fmaxf(var, 0.0f)) + EPSL);
    __shared__ float rowbuf[4][64];
    int t = threadIdx.x, d = t & 63, wv = t >> 6;
    int n = blockIdx.x * 4 + wv;
    float v = h1[n * DD + d];
    float h = fmaxf((v - mean) * rden * gw[d] + gb[d], 0.0f);
    h1[n * DD + d] = h;
    rowbuf[wv][d] = h;
    __syncthreads();
    float a0 = rbias[d], a1 = 0.f, a2 = 0.f, a3 = 0.f;
    #pragma unroll
    for (int i = 0; i < DD; i += 4) {
        a0 += rowbuf[wv][i]     * root[i * DD + d];
        a1 += rowbuf[wv][i + 1] * root[(i + 1) * DD + d];
        a2 += rowbuf[wv][i + 2] * root[(i + 2) * DD + d];
        a3 += rowbuf[wv][i + 3] * root[(i + 3) * DD + d];
    }
    agg2[n * DD + d] = (a0 + a1) + (a2 + a3);
}

// ---------------------------------------------------------------------------
// lnapply2 + pool fused
// ---------------------------------------------------------------------------
__global__ __launch_bounds__(256) void k_lnpool(const float* __restrict__ v,
                                                const float* __restrict__ stats,
                                                const float* __restrict__ gw,
                                                const float* __restrict__ gb,
                                                const int* __restrict__ batch,
                                                float* __restrict__ pool,
                                                float* __restrict__ cnt) {
    const float M = (float)(NN * DD);
    float mean = stats[0] / M;
    float var  = stats[1] / M - mean * mean;
    float rden = 1.0f / (sqrtf(fmaxf(var, 0.0f)) + EPSL);
    int t = threadIdx.x;
    int d = t & 63;
    int ln = t >> 6;
    int n0 = blockIdx.x * 256;
    float gwd = gw[d] * rden, gbd = gb[d];
    float s = 0.0f, sc = 0.0f;
    int cur = batch[n0 + ln];
    for (int j = 0; j < 64; ++j) {
        int n = n0 + ln + j * 4;
        int b = batch[n];
        if (b != cur) {
            atomicAdd(&pool[cur * DD + d], s);
            if (d == 0) atomicAdd(&cnt[cur], sc);
            s = 0.0f; sc = 0.0f; cur = b;
        }
        s  += fmaxf((v[n * DD + d] - mean) * gwd + gbd, 0.0f);
        sc += 1.0f;
    }
    atomicAdd(&pool[cur * DD + d], s);
    if (d == 0) atomicAdd(&cnt[cur], sc);
}

// ---------------------------------------------------------------------------
// fc2
// ---------------------------------------------------------------------------
__global__ __launch_bounds__(256) void k_fc2(const float* __restrict__ pool,
                                             const float* __restrict__ cnt,
                                             const float* __restrict__ w,
                                             const float* __restrict__ b,
                                             float* __restrict__ out) {
    int t = threadIdx.x;
    int o = t & 15;
    int g0 = t >> 4;
    #pragma unroll
    for (int gg = 0; gg < 4; ++gg) {
        int g = g0 + gg * 16;
        float inv = 1.0f / fmaxf(cnt[g], 1.0f);
        float acc = b[o];
        #pragma unroll
        for (int d = 0; d < DD; ++d)
            acc += pool[g * DD + d] * inv * w[d * OUTD + o];
        out[g * OUTD + o] = acc;
    }
}

// ---------------------------------------------------------------------------
extern "C" void kernel_launch(void* const* d_in, const int* in_sizes, int n_in,
                              void* d_out, int out_size, void* d_ws, size_t ws_size,
                              hipStream_t stream) {
    const float* x       = (const float*)d_in[0];
    const float* ea      = (const float*)d_in[1];
    const int*   ei      = (const int*)d_in[2];
    const int*   batch   = (const int*)d_in[3];
    const float* fc1_w   = (const float*)d_in[4];
    const float* fc1_b   = (const float*)d_in[5];
    const float* e1w1    = (const float*)d_in[6];
    const float* e1b1    = (const float*)d_in[7];
    const float* e1w2    = (const float*)d_in[8];
    const float* e1b2    = (const float*)d_in[9];
    const float* root1   = (const float*)d_in[10];
    const float* bias1   = (const float*)d_in[11];
    const float* gn1w    = (const float*)d_in[12];
    const float* gn1b    = (const float*)d_in[13];
    const float* e2w1    = (const float*)d_in[14];
    const float* e2b1    = (const float*)d_in[15];
    const float* e2w2    = (const float*)d_in[16];
    const float* e2b2    = (const float*)d_in[17];
    const float* root2   = (const float*)d_in[18];
    const float* bias2   = (const float*)d_in[19];
    const float* gn2w    = (const float*)d_in[20];
    const float* gn2b    = (const float*)d_in[21];
    const float* fc2_w   = (const float*)d_in[22];
    const float* fc2_b   = (const float*)d_in[23];
    float* out = (float*)d_out;

    // workspace layout (bytes)
    char* ws = (char*)d_ws;
    float*  hx    = (float*)(ws);                      // 8 MB; reused as agg2
    float*  agg1  = (float*)(ws + 8388608);            // 8 MB; becomes h1 in place
    __half* het   = (__half*)(ws + 16777216);          // 65*E fp16 = 12.78 MB
    __half* w2t   = (__half*)(ws + 29556736);          // 65*4096 fp16 = 520 KB
    float*  pool  = (float*)(ws + 30089216);           // 16 KB (+cnt 256B +stats 16B)
    float*  cnt   = (float*)(ws + 30105600);
    float*  stats = (float*)(ws + 30105856);
    float*  agg2  = hx;

    // ---- layer 1 ----  (conv1 block 0 zeroes stats[0..1])
    k_fc1agg<<<NN / 4, 256, 0, stream>>>(x, fc1_w, fc1_b, root1, bias1, hx, agg1);
    k_mlpprep<<<EE / 256, 256, 0, stream>>>(ea, e1w1, e1b1, het, e1w2, e1b2, w2t);
    k_conv<<<EE / EB, 256, 0, stream>>>(hx, het, w2t, ei, agg1, stats, 2);
    k_lnred<<<(NN * DD) / 4096, 256, 0, stream>>>(agg1, stats);
    k_lnagg<<<NN / 4, 256, 0, stream>>>(agg1, stats, gn1w, gn1b, root2, bias2, agg2);

    // ---- layer 2 ----  (conv2 block 0 zeroes stats[2..3] + pool + cnt)
    k_mlpprep<<<EE / 256, 256, 0, stream>>>(ea, e2w1, e2b1, het, e2w2, e2b2, w2t);
    k_conv<<<EE / EB, 256, 0, stream>>>(agg1, het, w2t, ei, agg2, pool, 4096 + 64 + 4);
    k_lnred<<<(NN * DD) / 4096, 256, 0, stream>>>(agg2, stats + 2);

    // ---- pool (fused with lnapply2) + fc2 ----
    k_lnpool<<<NN / 256, 256, 0, stream>>>(agg2, stats + 2, gn2w, gn2b, batch, pool, cnt);
    k_fc2<<<1, 256, 0, stream>>>(pool, cnt, fc2_w, fc2_b, out);
}